// Round 9
// baseline (166.062 us; speedup 1.0000x reference)
//
#include <hip/hip_runtime.h>

#define N_NODES   100000
#define N_EDGES   600000
#define D_FEAT    128
#define N_CLASSES 40

#define NPAD      100352            // N_NODES padded to 1024 multiple
#define SCAN_NBLK (NPAD / 1024)     // 98

// ================= CSR build =================

__global__ void k_zero(int4* __restrict__ deg4) {
    int i = blockIdx.x * blockDim.x + threadIdx.x;
    if (i < NPAD / 4) deg4[i] = make_int4(0, 0, 0, 0);
}

__global__ void k_count(const int* __restrict__ edst, int* __restrict__ deg) {
    int e = blockIdx.x * blockDim.x + threadIdx.x;
    if (e < N_EDGES) atomicAdd(&deg[edst[e]], 1);
}

// phase 1: per-block exclusive scan (1024 elems/block), local prefixes -> row_ptr
__global__ __launch_bounds__(256) void k_scan1(const int* __restrict__ deg,
                                               int* __restrict__ row_ptr,
                                               int* __restrict__ blksum) {
    __shared__ int wsum[4];
    int t = threadIdx.x;
    int lane = t & 63, w = t >> 6;
    int base = blockIdx.x * 1024 + t * 4;
    int4 v = *(const int4*)(deg + base);
    int s0 = v.x, s1 = s0 + v.y, s2 = s1 + v.z, s3 = s2 + v.w;
    int inc = s3;
#pragma unroll
    for (int d = 1; d < 64; d <<= 1) {
        int y = __shfl_up(inc, d, 64);
        if (lane >= d) inc += y;
    }
    if (lane == 63) wsum[w] = inc;
    __syncthreads();
    int woff = 0;
#pragma unroll
    for (int j = 0; j < 3; ++j) woff += (j < w) ? wsum[j] : 0;
    int texcl = woff + inc - s3;
    int4 o;
    o.x = texcl;
    o.y = texcl + s0;
    o.z = texcl + s1;
    o.w = texcl + s2;
    *(int4*)(row_ptr + base) = o;
    if (t == 255) blksum[blockIdx.x] = woff + inc;   // block total
}

// phase 2: add block offsets in place; emit cursor + dinv
__global__ __launch_bounds__(256) void k_scan2(const int* __restrict__ deg,
                                               int* __restrict__ row_ptr,
                                               int* __restrict__ cursor,
                                               float* __restrict__ dinv,
                                               const int* __restrict__ blksum) {
    __shared__ int s[SCAN_NBLK];
    int t = threadIdx.x;
    int blk = blockIdx.x;
    if (t < SCAN_NBLK) s[t] = blksum[t];
    __syncthreads();
    int off = 0;
    for (int j = 0; j < blk; ++j) off += s[j];
    int base = blk * 1024 + t * 4;
    int4 v = *(int4*)(row_ptr + base);
    v.x += off; v.y += off; v.z += off; v.w += off;
    *(int4*)(row_ptr + base) = v;
    *(int4*)(cursor + base) = v;
    int4 d = *(const int4*)(deg + base);
    float4 di;
    di.x = rsqrtf((float)(d.x + 1));
    di.y = rsqrtf((float)(d.y + 1));
    di.z = rsqrtf((float)(d.z + 1));
    di.w = rsqrtf((float)(d.w + 1));
    *(float4*)(dinv + base) = di;
    // row_ptr[N_NODES] = 600000 falls out of the scan (deg padding is zero)
}

__global__ void k_fill(const int* __restrict__ esrc, const int* __restrict__ edst,
                       int* __restrict__ cursor, int* __restrict__ csr_src) {
    int e = blockIdx.x * blockDim.x + threadIdx.x;
    if (e < N_EDGES) {
        int d = edst[e];
        int pos = atomicAdd(&cursor[d], 1);
        csr_src[pos] = esrc[e];
    }
}

// ================= u0 = (x @ W^T) * dinv[node] =================
// One node per thread, all 40 classes. Every lane reads the SAME W float4
// from LDS per step -> broadcast (no bank pressure); 160 FMA : 40 LDS instrs.
// 40 independent accumulator chains give deep ILP; x row loads (stride 512B
// per lane) unrolled x4 so 4 lines/lane are in flight under the FMA stream.

#define WROW 132

__global__ __launch_bounds__(256) void k_gemm(const float* __restrict__ x,
                                              const float* __restrict__ W,
                                              const float* __restrict__ dinv,
                                              float* __restrict__ y) {
    __shared__ float Wl[N_CLASSES][WROW];
    int t = threadIdx.x;

    for (int f = t; f < N_CLASSES * (D_FEAT / 4); f += 256) {
        int c = f >> 5, d4 = f & 31;
        float4 w = ((const float4*)W)[f];
        *(float4*)&Wl[c][d4 * 4] = w;
    }
    __syncthreads();

    int node = blockIdx.x * 256 + t;
    if (node >= N_NODES) return;

    const float4* xp = (const float4*)(x + (size_t)node * D_FEAT);

    float acc[N_CLASSES];
#pragma unroll
    for (int j = 0; j < N_CLASSES; ++j) acc[j] = 0.f;

    for (int d4 = 0; d4 < D_FEAT / 4; d4 += 4) {
        float4 xv[4];
#pragma unroll
        for (int u = 0; u < 4; ++u) xv[u] = xp[d4 + u];
#pragma unroll
        for (int u = 0; u < 4; ++u) {
#pragma unroll
            for (int j = 0; j < N_CLASSES; ++j) {
                float4 wv = *(const float4*)&Wl[j][(d4 + u) * 4];
                acc[j] += xv[u].x * wv.x + xv[u].y * wv.y
                        + xv[u].z * wv.z + xv[u].w * wv.w;
            }
        }
    }

    float di = dinv[node];
    float4* o = (float4*)(y + (size_t)node * N_CLASSES);
#pragma unroll
    for (int r = 0; r < 10; ++r) {
        o[r] = make_float4(acc[4 * r] * di, acc[4 * r + 1] * di,
                           acc[4 * r + 2] * di, acc[4 * r + 3] * di);
    }
}

// ================= CSR gather propagation on u (8 threads/node) =================
// u_out[d] = dinv[d]^2 * ( u_in[d] + sum_{s in N(d)} u_in[s] )
// thread role: sub = feature half (bit0), par = edge phase mod 4 (bits1-2).
// Wave covers 8 nodes; per-thread iterations = deg/4 (avg 1.5).

__global__ __launch_bounds__(256) void k_gather(const float* __restrict__ yin,
                                                float* __restrict__ yout,
                                                const float* __restrict__ dinv,
                                                const int* __restrict__ row_ptr,
                                                const int* __restrict__ csr_src) {
    int t = blockIdx.x * blockDim.x + threadIdx.x;
    int i = t >> 3;
    if (i >= N_NODES) return;
    int sub = t & 1;
    int par = (t >> 1) & 3;
    const float4* yb = (const float4*)yin;

    float4 a0, a1, a2, a3, a4;
    if (par == 0) {
        const float4* self = yb + (size_t)i * 10 + sub * 5;
        a0 = self[0]; a1 = self[1]; a2 = self[2]; a3 = self[3]; a4 = self[4];
    } else {
        a0 = a1 = a2 = a3 = a4 = make_float4(0.f, 0.f, 0.f, 0.f);
    }

    int e = row_ptr[i] + par, end = row_ptr[i + 1];
    for (; e < end; e += 4) {
        int s = csr_src[e];
        const float4* p = yb + (size_t)s * 10 + sub * 5;
        float4 v0 = p[0], v1 = p[1], v2 = p[2], v3 = p[3], v4 = p[4];
        a0.x += v0.x; a0.y += v0.y; a0.z += v0.z; a0.w += v0.w;
        a1.x += v1.x; a1.y += v1.y; a1.z += v1.z; a1.w += v1.w;
        a2.x += v2.x; a2.y += v2.y; a2.z += v2.z; a2.w += v2.w;
        a3.x += v3.x; a3.y += v3.y; a3.z += v3.z; a3.w += v3.w;
        a4.x += v4.x; a4.y += v4.y; a4.z += v4.z; a4.w += v4.w;
    }

    // combine edge-phase partial sums (bits 1 and 2)
#pragma unroll
    for (int d = 2; d <= 4; d <<= 1) {
        a0.x += __shfl_xor(a0.x, d); a0.y += __shfl_xor(a0.y, d); a0.z += __shfl_xor(a0.z, d); a0.w += __shfl_xor(a0.w, d);
        a1.x += __shfl_xor(a1.x, d); a1.y += __shfl_xor(a1.y, d); a1.z += __shfl_xor(a1.z, d); a1.w += __shfl_xor(a1.w, d);
        a2.x += __shfl_xor(a2.x, d); a2.y += __shfl_xor(a2.y, d); a2.z += __shfl_xor(a2.z, d); a2.w += __shfl_xor(a2.w, d);
        a3.x += __shfl_xor(a3.x, d); a3.y += __shfl_xor(a3.y, d); a3.z += __shfl_xor(a3.z, d); a3.w += __shfl_xor(a3.w, d);
        a4.x += __shfl_xor(a4.x, d); a4.y += __shfl_xor(a4.y, d); a4.z += __shfl_xor(a4.z, d); a4.w += __shfl_xor(a4.w, d);
    }

    if (par == 0) {
        float di = dinv[i];
        float s2 = di * di;
        float4* o = (float4*)yout + (size_t)i * 10 + sub * 5;
        o[0] = make_float4(a0.x * s2, a0.y * s2, a0.z * s2, a0.w * s2);
        o[1] = make_float4(a1.x * s2, a1.y * s2, a1.z * s2, a1.w * s2);
        o[2] = make_float4(a2.x * s2, a2.y * s2, a2.z * s2, a2.w * s2);
        o[3] = make_float4(a3.x * s2, a3.y * s2, a3.z * s2, a3.w * s2);
        o[4] = make_float4(a4.x * s2, a4.y * s2, a4.z * s2, a4.w * s2);
    }
}

// final round: logits = dinv[d]*v + b, then log_softmax
__global__ __launch_bounds__(256) void k_gather_out(const float* __restrict__ yin,
                                                    float* __restrict__ out,
                                                    const float* __restrict__ dinv,
                                                    const int* __restrict__ row_ptr,
                                                    const int* __restrict__ csr_src,
                                                    const float* __restrict__ bias) {
    int t = blockIdx.x * blockDim.x + threadIdx.x;
    int i = t >> 3;
    if (i >= N_NODES) return;
    int sub = t & 1;
    int par = (t >> 1) & 3;
    const float4* yb = (const float4*)yin;

    float4 a0, a1, a2, a3, a4;
    if (par == 0) {
        const float4* self = yb + (size_t)i * 10 + sub * 5;
        a0 = self[0]; a1 = self[1]; a2 = self[2]; a3 = self[3]; a4 = self[4];
    } else {
        a0 = a1 = a2 = a3 = a4 = make_float4(0.f, 0.f, 0.f, 0.f);
    }

    int e = row_ptr[i] + par, end = row_ptr[i + 1];
    for (; e < end; e += 4) {
        int s = csr_src[e];
        const float4* p = yb + (size_t)s * 10 + sub * 5;
        float4 v0 = p[0], v1 = p[1], v2 = p[2], v3 = p[3], v4 = p[4];
        a0.x += v0.x; a0.y += v0.y; a0.z += v0.z; a0.w += v0.w;
        a1.x += v1.x; a1.y += v1.y; a1.z += v1.z; a1.w += v1.w;
        a2.x += v2.x; a2.y += v2.y; a2.z += v2.z; a2.w += v2.w;
        a3.x += v3.x; a3.y += v3.y; a3.z += v3.z; a3.w += v3.w;
        a4.x += v4.x; a4.y += v4.y; a4.z += v4.z; a4.w += v4.w;
    }

#pragma unroll
    for (int d = 2; d <= 4; d <<= 1) {
        a0.x += __shfl_xor(a0.x, d); a0.y += __shfl_xor(a0.y, d); a0.z += __shfl_xor(a0.z, d); a0.w += __shfl_xor(a0.w, d);
        a1.x += __shfl_xor(a1.x, d); a1.y += __shfl_xor(a1.y, d); a1.z += __shfl_xor(a1.z, d); a1.w += __shfl_xor(a1.w, d);
        a2.x += __shfl_xor(a2.x, d); a2.y += __shfl_xor(a2.y, d); a2.z += __shfl_xor(a2.z, d); a2.w += __shfl_xor(a2.w, d);
        a3.x += __shfl_xor(a3.x, d); a3.y += __shfl_xor(a3.y, d); a3.z += __shfl_xor(a3.z, d); a3.w += __shfl_xor(a3.w, d);
        a4.x += __shfl_xor(a4.x, d); a4.y += __shfl_xor(a4.y, d); a4.z += __shfl_xor(a4.z, d); a4.w += __shfl_xor(a4.w, d);
    }

    float di = dinv[i];
    const float4* b4 = (const float4*)bias + sub * 5;
    float4 av[5] = {a0, a1, a2, a3, a4};
    float4 l[5];
    float m = -INFINITY;
#pragma unroll
    for (int r = 0; r < 5; ++r) {
        float4 b = b4[r];
        l[r].x = av[r].x * di + b.x;
        l[r].y = av[r].y * di + b.y;
        l[r].z = av[r].z * di + b.z;
        l[r].w = av[r].w * di + b.w;
        m = fmaxf(m, fmaxf(fmaxf(l[r].x, l[r].y), fmaxf(l[r].z, l[r].w)));
    }
    m = fmaxf(m, __shfl_xor(m, 1));     // combine feature halves (bit 0)
    float s = 0.f;
#pragma unroll
    for (int r = 0; r < 5; ++r) {
        s += __expf(l[r].x - m) + __expf(l[r].y - m)
           + __expf(l[r].z - m) + __expf(l[r].w - m);
    }
    s += __shfl_xor(s, 1);
    float lse = __logf(s) + m;

    if (par == 0) {
        float4* o = (float4*)out + (size_t)i * 10 + sub * 5;
#pragma unroll
        for (int r = 0; r < 5; ++r) {
            o[r] = make_float4(l[r].x - lse, l[r].y - lse, l[r].z - lse, l[r].w - lse);
        }
    }
}

// ================= launch =================

extern "C" void kernel_launch(void* const* d_in, const int* in_sizes, int n_in,
                              void* d_out, int out_size, void* d_ws, size_t ws_size,
                              hipStream_t stream) {
    const float* x   = (const float*)d_in[0];
    const int*   ei  = (const int*)d_in[1];
    const float* W   = (const float*)d_in[2];
    const float* b   = (const float*)d_in[3];
    float*       out = (float*)d_out;

    const int* esrc = ei;
    const int* edst = ei + N_EDGES;

    // workspace layout (4-byte elems, 16B-aligned sections)
    int*   deg     = (int*)d_ws;                       // NPAD
    int*   row_ptr = deg + NPAD;                       // NPAD (covers N_NODES+1)
    int*   cursor  = row_ptr + NPAD;                   // NPAD
    int*   blksum  = cursor + NPAD;                    // 128
    int*   csr_src = blksum + 128;                     // 600064
    float* dinv    = (float*)(csr_src + 600064);       // NPAD
    float* u0      = dinv + NPAD;                      // 4,000,000
    float* u1      = u0 + (size_t)N_NODES * N_CLASSES; // 4,000,000

    const int B = 256;
    const int gE = (N_EDGES + B - 1) / B;              // 2344
    const int gG = (8 * N_NODES + B - 1) / B;          // 3125 (8 threads/node)

    k_zero <<<(NPAD / 4 + B - 1) / B, B, 0, stream>>>((int4*)deg);
    k_count<<<gE, B, 0, stream>>>(edst, deg);
    k_scan1<<<SCAN_NBLK, B, 0, stream>>>(deg, row_ptr, blksum);
    k_scan2<<<SCAN_NBLK, B, 0, stream>>>(deg, row_ptr, cursor, dinv, blksum);
    k_fill <<<gE, B, 0, stream>>>(esrc, edst, cursor, csr_src);

    k_gemm<<<(N_NODES + 255) / 256, B, 0, stream>>>(x, W, dinv, u0);

    k_gather    <<<gG, B, 0, stream>>>(u0, u1, dinv, row_ptr, csr_src);
    k_gather_out<<<gG, B, 0, stream>>>(u1, out, dinv, row_ptr, csr_src, b);
}

// Round 10
// 159.868 us; speedup vs baseline: 1.0387x; 1.0387x over previous
//
#include <hip/hip_runtime.h>

#define N_NODES   100000
#define N_EDGES   600000
#define D_FEAT    128
#define N_CLASSES 40
#define USTRIDE   64                // bf16 elems/row -> 128 B, one cache line

#define NPAD      100352            // N_NODES padded to 1024 multiple
#define SCAN_NBLK (NPAD / 1024)     // 98

// ---------- bf16 helpers (RTNE) ----------
__device__ __forceinline__ float bf2f(unsigned int h) { return __uint_as_float(h << 16); }
__device__ __forceinline__ unsigned int f2bf(float f) {
    unsigned int u = __float_as_uint(f);
    return (u + 0x7FFFu + ((u >> 16) & 1u)) >> 16;
}
__device__ __forceinline__ float4 up4(uint2 v) {
    return make_float4(bf2f(v.x & 0xFFFFu), bf2f(v.x >> 16),
                       bf2f(v.y & 0xFFFFu), bf2f(v.y >> 16));
}
__device__ __forceinline__ uint2 pk4(float4 f) {
    uint2 r;
    r.x = f2bf(f.x) | (f2bf(f.y) << 16);
    r.y = f2bf(f.z) | (f2bf(f.w) << 16);
    return r;
}

// ================= CSR build =================

__global__ void k_zero(int4* __restrict__ deg4) {
    int i = blockIdx.x * blockDim.x + threadIdx.x;
    if (i < NPAD / 4) deg4[i] = make_int4(0, 0, 0, 0);
}

__global__ void k_count(const int* __restrict__ edst, int* __restrict__ deg) {
    int e = blockIdx.x * blockDim.x + threadIdx.x;
    if (e < N_EDGES) atomicAdd(&deg[edst[e]], 1);
}

__global__ __launch_bounds__(256) void k_scan1(const int* __restrict__ deg,
                                               int* __restrict__ row_ptr,
                                               int* __restrict__ blksum) {
    __shared__ int wsum[4];
    int t = threadIdx.x;
    int lane = t & 63, w = t >> 6;
    int base = blockIdx.x * 1024 + t * 4;
    int4 v = *(const int4*)(deg + base);
    int s0 = v.x, s1 = s0 + v.y, s2 = s1 + v.z, s3 = s2 + v.w;
    int inc = s3;
#pragma unroll
    for (int d = 1; d < 64; d <<= 1) {
        int y = __shfl_up(inc, d, 64);
        if (lane >= d) inc += y;
    }
    if (lane == 63) wsum[w] = inc;
    __syncthreads();
    int woff = 0;
#pragma unroll
    for (int j = 0; j < 3; ++j) woff += (j < w) ? wsum[j] : 0;
    int texcl = woff + inc - s3;
    int4 o;
    o.x = texcl; o.y = texcl + s0; o.z = texcl + s1; o.w = texcl + s2;
    *(int4*)(row_ptr + base) = o;
    if (t == 255) blksum[blockIdx.x] = woff + inc;
}

__global__ __launch_bounds__(256) void k_scan2(const int* __restrict__ deg,
                                               int* __restrict__ row_ptr,
                                               int* __restrict__ cursor,
                                               float* __restrict__ dinv,
                                               const int* __restrict__ blksum) {
    __shared__ int s[SCAN_NBLK];
    int t = threadIdx.x;
    int blk = blockIdx.x;
    if (t < SCAN_NBLK) s[t] = blksum[t];
    __syncthreads();
    int off = 0;
    for (int j = 0; j < blk; ++j) off += s[j];
    int base = blk * 1024 + t * 4;
    int4 v = *(int4*)(row_ptr + base);
    v.x += off; v.y += off; v.z += off; v.w += off;
    *(int4*)(row_ptr + base) = v;
    *(int4*)(cursor + base) = v;
    int4 d = *(const int4*)(deg + base);
    float4 di;
    di.x = rsqrtf((float)(d.x + 1));
    di.y = rsqrtf((float)(d.y + 1));
    di.z = rsqrtf((float)(d.z + 1));
    di.w = rsqrtf((float)(d.w + 1));
    *(float4*)(dinv + base) = di;
}

__global__ void k_fill(const int* __restrict__ esrc, const int* __restrict__ edst,
                       int* __restrict__ cursor, int* __restrict__ csr_src) {
    int e = blockIdx.x * blockDim.x + threadIdx.x;
    if (e < N_EDGES) {
        int d = edst[e];
        int pos = atomicAdd(&cursor[d], 1);
        csr_src[pos] = esrc[e];
    }
}

// ================= u0 = bf16( (x @ W^T) * dinv[node] ) =================
// 256 thr = 64 quads x 2 nodes, 128 nodes/block, grid 782 (~3 blk/CU).
// Cross-iteration register double-buffer: next 8 x-float4s issue before
// current 320 FMAs -> HBM/L3 latency hidden under the FMA stream.

#define WROW 132

__global__ __launch_bounds__(256) void k_gemm(const float* __restrict__ x,
                                              const float* __restrict__ W,
                                              const float* __restrict__ dinv,
                                              unsigned short* __restrict__ y) {
    __shared__ float Wl[N_CLASSES][WROW];
    int t = threadIdx.x;

    for (int f = t; f < N_CLASSES * (D_FEAT / 4); f += 256) {
        int c = f >> 5, d4 = f & 31;
        float4 w = ((const float4*)W)[f];
        *(float4*)&Wl[c][d4 * 4] = w;
    }
    __syncthreads();

    int quad = t >> 2;
    int sub  = t & 3;
    int c0   = sub * 10;
    int n0   = blockIdx.x * 128 + quad * 2;
    if (n0 >= N_NODES) return;

    const float4* xp = (const float4*)(x + (size_t)n0 * D_FEAT);

    float acc[2][10];
#pragma unroll
    for (int k = 0; k < 2; ++k)
#pragma unroll
        for (int j = 0; j < 10; ++j) acc[k][j] = 0.f;

    float4 xa[4], xb[4];
#pragma unroll
    for (int u = 0; u < 4; ++u) { xa[u] = xp[u]; xb[u] = xp[32 + u]; }

#pragma unroll
    for (int d4 = 0; d4 < 32; d4 += 4) {
        float4 na[4], nb[4];
        if (d4 + 4 < 32) {
#pragma unroll
            for (int u = 0; u < 4; ++u) {
                na[u] = xp[d4 + 4 + u];
                nb[u] = xp[32 + d4 + 4 + u];
            }
        }
#pragma unroll
        for (int u = 0; u < 4; ++u) {
#pragma unroll
            for (int j = 0; j < 10; ++j) {
                float4 wv = *(const float4*)&Wl[c0 + j][(d4 + u) * 4];
                acc[0][j] += xa[u].x * wv.x + xa[u].y * wv.y + xa[u].z * wv.z + xa[u].w * wv.w;
                acc[1][j] += xb[u].x * wv.x + xb[u].y * wv.y + xb[u].z * wv.z + xb[u].w * wv.w;
            }
        }
        if (d4 + 4 < 32) {
#pragma unroll
            for (int u = 0; u < 4; ++u) { xa[u] = na[u]; xb[u] = nb[u]; }
        }
    }

    unsigned int* up = (unsigned int*)y;
#pragma unroll
    for (int k = 0; k < 2; ++k) {
        float di = dinv[n0 + k];
#pragma unroll
        for (int p = 0; p < 5; ++p) {
            unsigned int w = f2bf(acc[k][2 * p] * di) | (f2bf(acc[k][2 * p + 1] * di) << 16);
            up[(size_t)(n0 + k) * (USTRIDE / 2) + sub * 5 + p] = w;
        }
    }
}

// ================= CSR gather on bf16 u (4 threads/node) =================
// u_out[d] = dinv[d]^2 * ( u_in[d] + sum u_in[s] ); rows are ONE 128B line.
// sub = class half (bit0, 20 classes = 5 uint2 = 40B), par = edge parity (bit1).

__global__ __launch_bounds__(256) void k_gather(const unsigned short* __restrict__ yin,
                                                unsigned short* __restrict__ yout,
                                                const float* __restrict__ dinv,
                                                const int* __restrict__ row_ptr,
                                                const int* __restrict__ csr_src) {
    int t = blockIdx.x * blockDim.x + threadIdx.x;
    int i = t >> 2;
    if (i >= N_NODES) return;
    int sub = t & 1;
    int par = (t >> 1) & 1;
    const uint2* yb = (const uint2*)yin;

    float4 a[5];
    if (par == 0) {
        const uint2* self = yb + (size_t)i * 16 + sub * 5;
#pragma unroll
        for (int r = 0; r < 5; ++r) a[r] = up4(self[r]);
    } else {
#pragma unroll
        for (int r = 0; r < 5; ++r) a[r] = make_float4(0.f, 0.f, 0.f, 0.f);
    }

    int e = row_ptr[i] + par, end = row_ptr[i + 1];
    for (; e + 2 < end; e += 4) {
        int s0 = csr_src[e], s1 = csr_src[e + 2];
        const uint2* p0 = yb + (size_t)s0 * 16 + sub * 5;
        const uint2* p1 = yb + (size_t)s1 * 16 + sub * 5;
        uint2 w0[5], w1[5];
#pragma unroll
        for (int r = 0; r < 5; ++r) w0[r] = p0[r];
#pragma unroll
        for (int r = 0; r < 5; ++r) w1[r] = p1[r];
#pragma unroll
        for (int r = 0; r < 5; ++r) {
            float4 v0 = up4(w0[r]), v1 = up4(w1[r]);
            a[r].x += v0.x + v1.x; a[r].y += v0.y + v1.y;
            a[r].z += v0.z + v1.z; a[r].w += v0.w + v1.w;
        }
    }
    if (e < end) {
        int s0 = csr_src[e];
        const uint2* p0 = yb + (size_t)s0 * 16 + sub * 5;
#pragma unroll
        for (int r = 0; r < 5; ++r) {
            float4 v0 = up4(p0[r]);
            a[r].x += v0.x; a[r].y += v0.y; a[r].z += v0.z; a[r].w += v0.w;
        }
    }

#pragma unroll
    for (int r = 0; r < 5; ++r) {
        a[r].x += __shfl_xor(a[r].x, 2); a[r].y += __shfl_xor(a[r].y, 2);
        a[r].z += __shfl_xor(a[r].z, 2); a[r].w += __shfl_xor(a[r].w, 2);
    }

    if (par == 0) {
        float di = dinv[i];
        float s2 = di * di;
        uint2* o = (uint2*)yout + (size_t)i * 16 + sub * 5;
#pragma unroll
        for (int r = 0; r < 5; ++r) {
            o[r] = pk4(make_float4(a[r].x * s2, a[r].y * s2, a[r].z * s2, a[r].w * s2));
        }
    }
}

// final round: logits = dinv*v + b, log_softmax, fp32 out
__global__ __launch_bounds__(256) void k_gather_out(const unsigned short* __restrict__ yin,
                                                    float* __restrict__ out,
                                                    const float* __restrict__ dinv,
                                                    const int* __restrict__ row_ptr,
                                                    const int* __restrict__ csr_src,
                                                    const float* __restrict__ bias) {
    int t = blockIdx.x * blockDim.x + threadIdx.x;
    int i = t >> 2;
    if (i >= N_NODES) return;
    int sub = t & 1;
    int par = (t >> 1) & 1;
    const uint2* yb = (const uint2*)yin;

    float4 a[5];
    if (par == 0) {
        const uint2* self = yb + (size_t)i * 16 + sub * 5;
#pragma unroll
        for (int r = 0; r < 5; ++r) a[r] = up4(self[r]);
    } else {
#pragma unroll
        for (int r = 0; r < 5; ++r) a[r] = make_float4(0.f, 0.f, 0.f, 0.f);
    }

    int e = row_ptr[i] + par, end = row_ptr[i + 1];
    for (; e + 2 < end; e += 4) {
        int s0 = csr_src[e], s1 = csr_src[e + 2];
        const uint2* p0 = yb + (size_t)s0 * 16 + sub * 5;
        const uint2* p1 = yb + (size_t)s1 * 16 + sub * 5;
        uint2 w0[5], w1[5];
#pragma unroll
        for (int r = 0; r < 5; ++r) w0[r] = p0[r];
#pragma unroll
        for (int r = 0; r < 5; ++r) w1[r] = p1[r];
#pragma unroll
        for (int r = 0; r < 5; ++r) {
            float4 v0 = up4(w0[r]), v1 = up4(w1[r]);
            a[r].x += v0.x + v1.x; a[r].y += v0.y + v1.y;
            a[r].z += v0.z + v1.z; a[r].w += v0.w + v1.w;
        }
    }
    if (e < end) {
        int s0 = csr_src[e];
        const uint2* p0 = yb + (size_t)s0 * 16 + sub * 5;
#pragma unroll
        for (int r = 0; r < 5; ++r) {
            float4 v0 = up4(p0[r]);
            a[r].x += v0.x; a[r].y += v0.y; a[r].z += v0.z; a[r].w += v0.w;
        }
    }

#pragma unroll
    for (int r = 0; r < 5; ++r) {
        a[r].x += __shfl_xor(a[r].x, 2); a[r].y += __shfl_xor(a[r].y, 2);
        a[r].z += __shfl_xor(a[r].z, 2); a[r].w += __shfl_xor(a[r].w, 2);
    }

    float di = dinv[i];
    const float4* b4 = (const float4*)bias + sub * 5;
    float4 l[5];
    float m = -INFINITY;
#pragma unroll
    for (int r = 0; r < 5; ++r) {
        float4 b = b4[r];
        l[r].x = a[r].x * di + b.x;
        l[r].y = a[r].y * di + b.y;
        l[r].z = a[r].z * di + b.z;
        l[r].w = a[r].w * di + b.w;
        m = fmaxf(m, fmaxf(fmaxf(l[r].x, l[r].y), fmaxf(l[r].z, l[r].w)));
    }
    m = fmaxf(m, __shfl_xor(m, 1));
    float s = 0.f;
#pragma unroll
    for (int r = 0; r < 5; ++r) {
        s += __expf(l[r].x - m) + __expf(l[r].y - m)
           + __expf(l[r].z - m) + __expf(l[r].w - m);
    }
    s += __shfl_xor(s, 1);
    float lse = __logf(s) + m;

    if (par == 0) {
        float4* o = (float4*)out + (size_t)i * 10 + sub * 5;
#pragma unroll
        for (int r = 0; r < 5; ++r) {
            o[r] = make_float4(l[r].x - lse, l[r].y - lse, l[r].z - lse, l[r].w - lse);
        }
    }
}

// ================= launch =================

extern "C" void kernel_launch(void* const* d_in, const int* in_sizes, int n_in,
                              void* d_out, int out_size, void* d_ws, size_t ws_size,
                              hipStream_t stream) {
    const float* x   = (const float*)d_in[0];
    const int*   ei  = (const int*)d_in[1];
    const float* W   = (const float*)d_in[2];
    const float* b   = (const float*)d_in[3];
    float*       out = (float*)d_out;

    const int* esrc = ei;
    const int* edst = ei + N_EDGES;

    // workspace layout
    int*   deg     = (int*)d_ws;                       // NPAD
    int*   row_ptr = deg + NPAD;                       // NPAD
    int*   cursor  = row_ptr + NPAD;                   // NPAD
    int*   blksum  = cursor + NPAD;                    // 128
    int*   csr_src = blksum + 128;                     // 600064
    float* dinv    = (float*)(csr_src + 600064);       // NPAD
    unsigned short* u0 = (unsigned short*)(dinv + NPAD);        // 100000*64 bf16 (12.8MB)
    unsigned short* u1 = u0 + (size_t)N_NODES * USTRIDE;        // 12.8MB

    const int B = 256;
    const int gE = (N_EDGES + B - 1) / B;              // 2344
    const int gG = (4 * N_NODES + B - 1) / B;          // 1563

    k_zero <<<(NPAD / 4 + B - 1) / B, B, 0, stream>>>((int4*)deg);
    k_count<<<gE, B, 0, stream>>>(edst, deg);
    k_scan1<<<SCAN_NBLK, B, 0, stream>>>(deg, row_ptr, blksum);
    k_scan2<<<SCAN_NBLK, B, 0, stream>>>(deg, row_ptr, cursor, dinv, blksum);
    k_fill <<<gE, B, 0, stream>>>(esrc, edst, cursor, csr_src);

    k_gemm<<<(N_NODES + 127) / 128, B, 0, stream>>>(x, W, dinv, u0);

    k_gather    <<<gG, B, 0, stream>>>(u0, u1, dinv, row_ptr, csr_src);
    k_gather_out<<<gG, B, 0, stream>>>(u1, out, dinv, row_ptr, csr_src, b);
}

// Round 11
// 136.518 us; speedup vs baseline: 1.2164x; 1.1710x over previous
//
#include <hip/hip_runtime.h>

#define N_NODES   100000
#define N_EDGES   600000
#define D_FEAT    128
#define N_CLASSES 40
#define USTRIDE   64                // bf16 elems/row -> 128 B, one cache line

#define NPAD      100352            // N_NODES padded to 1024 multiple
#define SCAN_NBLK (NPAD / 1024)     // 98

// ---------- bf16 helpers (RTNE) ----------
__device__ __forceinline__ float bf2f(unsigned int h) { return __uint_as_float(h << 16); }
__device__ __forceinline__ unsigned int f2bf(float f) {
    unsigned int u = __float_as_uint(f);
    return (u + 0x7FFFu + ((u >> 16) & 1u)) >> 16;
}
__device__ __forceinline__ float4 up4(uint2 v) {
    return make_float4(bf2f(v.x & 0xFFFFu), bf2f(v.x >> 16),
                       bf2f(v.y & 0xFFFFu), bf2f(v.y >> 16));
}
__device__ __forceinline__ uint2 pk4(float4 f) {
    uint2 r;
    r.x = f2bf(f.x) | (f2bf(f.y) << 16);
    r.y = f2bf(f.z) | (f2bf(f.w) << 16);
    return r;
}

// ================= CSR build =================

__global__ void k_zero(int4* __restrict__ deg4) {
    int i = blockIdx.x * blockDim.x + threadIdx.x;
    if (i < NPAD / 4) deg4[i] = make_int4(0, 0, 0, 0);
}

__global__ void k_count(const int* __restrict__ edst, int* __restrict__ deg) {
    int e = blockIdx.x * blockDim.x + threadIdx.x;
    if (e < N_EDGES) atomicAdd(&deg[edst[e]], 1);
}

__global__ __launch_bounds__(256) void k_scan1(const int* __restrict__ deg,
                                               int* __restrict__ row_ptr,
                                               int* __restrict__ blksum) {
    __shared__ int wsum[4];
    int t = threadIdx.x;
    int lane = t & 63, w = t >> 6;
    int base = blockIdx.x * 1024 + t * 4;
    int4 v = *(const int4*)(deg + base);
    int s0 = v.x, s1 = s0 + v.y, s2 = s1 + v.z, s3 = s2 + v.w;
    int inc = s3;
#pragma unroll
    for (int d = 1; d < 64; d <<= 1) {
        int y = __shfl_up(inc, d, 64);
        if (lane >= d) inc += y;
    }
    if (lane == 63) wsum[w] = inc;
    __syncthreads();
    int woff = 0;
#pragma unroll
    for (int j = 0; j < 3; ++j) woff += (j < w) ? wsum[j] : 0;
    int texcl = woff + inc - s3;
    int4 o;
    o.x = texcl; o.y = texcl + s0; o.z = texcl + s1; o.w = texcl + s2;
    *(int4*)(row_ptr + base) = o;
    if (t == 255) blksum[blockIdx.x] = woff + inc;
}

__global__ __launch_bounds__(256) void k_scan2(const int* __restrict__ deg,
                                               int* __restrict__ row_ptr,
                                               int* __restrict__ cursor,
                                               float* __restrict__ dinv,
                                               const int* __restrict__ blksum) {
    __shared__ int s[SCAN_NBLK];
    int t = threadIdx.x;
    int blk = blockIdx.x;
    if (t < SCAN_NBLK) s[t] = blksum[t];
    __syncthreads();
    int off = 0;
    for (int j = 0; j < blk; ++j) off += s[j];
    int base = blk * 1024 + t * 4;
    int4 v = *(int4*)(row_ptr + base);
    v.x += off; v.y += off; v.z += off; v.w += off;
    *(int4*)(row_ptr + base) = v;
    *(int4*)(cursor + base) = v;
    int4 d = *(const int4*)(deg + base);
    float4 di;
    di.x = rsqrtf((float)(d.x + 1));
    di.y = rsqrtf((float)(d.y + 1));
    di.z = rsqrtf((float)(d.z + 1));
    di.w = rsqrtf((float)(d.w + 1));
    *(float4*)(dinv + base) = di;
}

__global__ void k_fill(const int* __restrict__ esrc, const int* __restrict__ edst,
                       int* __restrict__ cursor, int* __restrict__ csr_src) {
    int e = blockIdx.x * blockDim.x + threadIdx.x;
    if (e < N_EDGES) {
        int d = edst[e];
        int pos = atomicAdd(&cursor[d], 1);
        csr_src[pos] = esrc[e];
    }
}

// ================= u0 = bf16( (x @ W^T) * dinv[node] ) =================
// 1 node per quad (4 threads x 10 classes): 400k threads = 6250 waves (6/SIMD)
// for latency tolerance. Per d4-iter: 1 quad-broadcast global load + 10 LDS
// b128 (16-lane broadcast each, conflict-free) + 40 FMAs. No hand prefetch
// arrays (round-10 lesson: VGPR 240 -> occupancy collapse).

#define WROW 132

__global__ __launch_bounds__(256) void k_gemm(const float* __restrict__ x,
                                              const float* __restrict__ W,
                                              const float* __restrict__ dinv,
                                              unsigned short* __restrict__ y) {
    __shared__ float Wl[N_CLASSES][WROW];
    int t = threadIdx.x;

    for (int f = t; f < N_CLASSES * (D_FEAT / 4); f += 256) {
        int c = f >> 5, d4 = f & 31;
        float4 w = ((const float4*)W)[f];
        *(float4*)&Wl[c][d4 * 4] = w;
    }
    __syncthreads();

    int quad = t >> 2;                    // 0..63
    int sub  = t & 3;
    int c0   = sub * 10;
    int node = blockIdx.x * 64 + quad;
    if (node >= N_NODES) return;

    const float4* xp = (const float4*)(x + (size_t)node * D_FEAT);

    float acc[10];
#pragma unroll
    for (int j = 0; j < 10; ++j) acc[j] = 0.f;

    for (int d4 = 0; d4 < D_FEAT / 4; d4 += 2) {
        float4 x0 = xp[d4];
        float4 x1 = xp[d4 + 1];
#pragma unroll
        for (int j = 0; j < 10; ++j) {
            float4 w0 = *(const float4*)&Wl[c0 + j][d4 * 4];
            float4 w1 = *(const float4*)&Wl[c0 + j][(d4 + 1) * 4];
            acc[j] += x0.x * w0.x + x0.y * w0.y + x0.z * w0.z + x0.w * w0.w
                    + x1.x * w1.x + x1.y * w1.y + x1.z * w1.z + x1.w * w1.w;
        }
    }

    float di = dinv[node];
    unsigned int* up = (unsigned int*)y;
#pragma unroll
    for (int p = 0; p < 5; ++p) {
        unsigned int w = f2bf(acc[2 * p] * di) | (f2bf(acc[2 * p + 1] * di) << 16);
        up[(size_t)node * (USTRIDE / 2) + sub * 5 + p] = w;
    }
}

// ================= CSR gather on bf16 u (8 threads/node) =================
// u_out[d] = dinv[d]^2 * ( u_in[d] + sum u_in[s] ); rows are ONE 128B line.
// sub = class half (bit0, 5 uint2 = 40B), par = edge phase mod 4 (bits1-2).
// 12500 waves for the latency-bound random-row loop (avg 1.5 iters/thread).

__global__ __launch_bounds__(256) void k_gather(const unsigned short* __restrict__ yin,
                                                unsigned short* __restrict__ yout,
                                                const float* __restrict__ dinv,
                                                const int* __restrict__ row_ptr,
                                                const int* __restrict__ csr_src) {
    int t = blockIdx.x * blockDim.x + threadIdx.x;
    int i = t >> 3;
    if (i >= N_NODES) return;
    int sub = t & 1;
    int par = (t >> 1) & 3;
    const uint2* yb = (const uint2*)yin;

    float4 a[5];
    if (par == 0) {
        const uint2* self = yb + (size_t)i * 16 + sub * 5;
#pragma unroll
        for (int r = 0; r < 5; ++r) a[r] = up4(self[r]);
    } else {
#pragma unroll
        for (int r = 0; r < 5; ++r) a[r] = make_float4(0.f, 0.f, 0.f, 0.f);
    }

    int e = row_ptr[i] + par, end = row_ptr[i + 1];
    for (; e < end; e += 4) {
        int s = csr_src[e];
        const uint2* p = yb + (size_t)s * 16 + sub * 5;
        uint2 w[5];
#pragma unroll
        for (int r = 0; r < 5; ++r) w[r] = p[r];
#pragma unroll
        for (int r = 0; r < 5; ++r) {
            float4 v = up4(w[r]);
            a[r].x += v.x; a[r].y += v.y; a[r].z += v.z; a[r].w += v.w;
        }
    }

    // combine edge-phase partial sums (bits 1 and 2)
#pragma unroll
    for (int d = 2; d <= 4; d <<= 1) {
#pragma unroll
        for (int r = 0; r < 5; ++r) {
            a[r].x += __shfl_xor(a[r].x, d); a[r].y += __shfl_xor(a[r].y, d);
            a[r].z += __shfl_xor(a[r].z, d); a[r].w += __shfl_xor(a[r].w, d);
        }
    }

    if (par == 0) {
        float di = dinv[i];
        float s2 = di * di;
        uint2* o = (uint2*)yout + (size_t)i * 16 + sub * 5;
#pragma unroll
        for (int r = 0; r < 5; ++r) {
            o[r] = pk4(make_float4(a[r].x * s2, a[r].y * s2, a[r].z * s2, a[r].w * s2));
        }
    }
}

// final round: logits = dinv*v + b, log_softmax, fp32 out
__global__ __launch_bounds__(256) void k_gather_out(const unsigned short* __restrict__ yin,
                                                    float* __restrict__ out,
                                                    const float* __restrict__ dinv,
                                                    const int* __restrict__ row_ptr,
                                                    const int* __restrict__ csr_src,
                                                    const float* __restrict__ bias) {
    int t = blockIdx.x * blockDim.x + threadIdx.x;
    int i = t >> 3;
    if (i >= N_NODES) return;
    int sub = t & 1;
    int par = (t >> 1) & 3;
    const uint2* yb = (const uint2*)yin;

    float4 a[5];
    if (par == 0) {
        const uint2* self = yb + (size_t)i * 16 + sub * 5;
#pragma unroll
        for (int r = 0; r < 5; ++r) a[r] = up4(self[r]);
    } else {
#pragma unroll
        for (int r = 0; r < 5; ++r) a[r] = make_float4(0.f, 0.f, 0.f, 0.f);
    }

    int e = row_ptr[i] + par, end = row_ptr[i + 1];
    for (; e < end; e += 4) {
        int s = csr_src[e];
        const uint2* p = yb + (size_t)s * 16 + sub * 5;
        uint2 w[5];
#pragma unroll
        for (int r = 0; r < 5; ++r) w[r] = p[r];
#pragma unroll
        for (int r = 0; r < 5; ++r) {
            float4 v = up4(w[r]);
            a[r].x += v.x; a[r].y += v.y; a[r].z += v.z; a[r].w += v.w;
        }
    }

#pragma unroll
    for (int d = 2; d <= 4; d <<= 1) {
#pragma unroll
        for (int r = 0; r < 5; ++r) {
            a[r].x += __shfl_xor(a[r].x, d); a[r].y += __shfl_xor(a[r].y, d);
            a[r].z += __shfl_xor(a[r].z, d); a[r].w += __shfl_xor(a[r].w, d);
        }
    }

    float di = dinv[i];
    const float4* b4 = (const float4*)bias + sub * 5;
    float4 l[5];
    float m = -INFINITY;
#pragma unroll
    for (int r = 0; r < 5; ++r) {
        float4 b = b4[r];
        l[r].x = a[r].x * di + b.x;
        l[r].y = a[r].y * di + b.y;
        l[r].z = a[r].z * di + b.z;
        l[r].w = a[r].w * di + b.w;
        m = fmaxf(m, fmaxf(fmaxf(l[r].x, l[r].y), fmaxf(l[r].z, l[r].w)));
    }
    m = fmaxf(m, __shfl_xor(m, 1));     // combine class halves (bit 0)
    float s = 0.f;
#pragma unroll
    for (int r = 0; r < 5; ++r) {
        s += __expf(l[r].x - m) + __expf(l[r].y - m)
           + __expf(l[r].z - m) + __expf(l[r].w - m);
    }
    s += __shfl_xor(s, 1);
    float lse = __logf(s) + m;

    if (par == 0) {
        float4* o = (float4*)out + (size_t)i * 10 + sub * 5;
#pragma unroll
        for (int r = 0; r < 5; ++r) {
            o[r] = make_float4(l[r].x - lse, l[r].y - lse, l[r].z - lse, l[r].w - lse);
        }
    }
}

// ================= launch =================

extern "C" void kernel_launch(void* const* d_in, const int* in_sizes, int n_in,
                              void* d_out, int out_size, void* d_ws, size_t ws_size,
                              hipStream_t stream) {
    const float* x   = (const float*)d_in[0];
    const int*   ei  = (const int*)d_in[1];
    const float* W   = (const float*)d_in[2];
    const float* b   = (const float*)d_in[3];
    float*       out = (float*)d_out;

    const int* esrc = ei;
    const int* edst = ei + N_EDGES;

    // workspace layout
    int*   deg     = (int*)d_ws;                       // NPAD
    int*   row_ptr = deg + NPAD;                       // NPAD
    int*   cursor  = row_ptr + NPAD;                   // NPAD
    int*   blksum  = cursor + NPAD;                    // 128
    int*   csr_src = blksum + 128;                     // 600064
    float* dinv    = (float*)(csr_src + 600064);       // NPAD
    unsigned short* u0 = (unsigned short*)(dinv + NPAD);        // 100000*64 bf16
    unsigned short* u1 = u0 + (size_t)N_NODES * USTRIDE;

    const int B = 256;
    const int gE = (N_EDGES + B - 1) / B;              // 2344
    const int gG = (8 * N_NODES + B - 1) / B;          // 3125

    k_zero <<<(NPAD / 4 + B - 1) / B, B, 0, stream>>>((int4*)deg);
    k_count<<<gE, B, 0, stream>>>(edst, deg);
    k_scan1<<<SCAN_NBLK, B, 0, stream>>>(deg, row_ptr, blksum);
    k_scan2<<<SCAN_NBLK, B, 0, stream>>>(deg, row_ptr, cursor, dinv, blksum);
    k_fill <<<gE, B, 0, stream>>>(esrc, edst, cursor, csr_src);

    k_gemm<<<(N_NODES + 63) / 64, B, 0, stream>>>(x, W, dinv, u0);

    k_gather    <<<gG, B, 0, stream>>>(u0, u1, dinv, row_ptr, csr_src);
    k_gather_out<<<gG, B, 0, stream>>>(u1, out, dinv, row_ptr, csr_src, b);
}